// Round 9
// baseline (1310.357 us; speedup 1.0000x reference)
//
#include <hip/hip_runtime.h>
#include <hip/hip_bf16.h>

#define T_STEPS 2048
#define BATCH   256
#define DIM     128
#define INV2PI  0.15915494309189535f

#define ZX_FLOATS (T_STEPS * BATCH * 16)   // 33.5 MB
#define NTILES   8192                      // 64-row tiles over T*B rows
#define NWIN     64                        // 32-step windows
#define TPW      128                       // tiles per window
#define NGEMMW   960                       // gemm waves (1024 total - 64 rec)

// ---------------------------------------------------------------------------
// prep: pack Wc[d*16+(g*4+k)] = W_g[d*4+k]/2pi, bt[u] = (b+theta)/2pi,
// and re-zero the window counters.
// ---------------------------------------------------------------------------
__global__ __launch_bounds__(64) void prep(
    const float* __restrict__ Wf, const float* __restrict__ bf, const float* __restrict__ tf,
    const float* __restrict__ Wi, const float* __restrict__ bi, const float* __restrict__ ti,
    const float* __restrict__ Wu, const float* __restrict__ bu, const float* __restrict__ tu,
    const float* __restrict__ Wo, const float* __restrict__ bo, const float* __restrict__ to_,
    float* __restrict__ Wc, float* __restrict__ bt, unsigned int* __restrict__ wcnt)
{
    const int tid = threadIdx.x;
    for (int idx = tid; idx < DIM * 16; idx += 64) {
        int d = idx >> 4, u = idx & 15, g = u >> 2, k = u & 3;
        const float* W = (g == 0) ? Wf : (g == 1) ? Wi : (g == 2) ? Wu : Wo;
        Wc[idx] = W[d * 4 + k] * INV2PI;
    }
    if (tid < 16) {
        int g = tid >> 2, k = tid & 3;
        const float* bb = (g == 0) ? bf : (g == 1) ? bi : (g == 2) ? bu : bo;
        const float* tt = (g == 0) ? tf : (g == 1) ? ti : (g == 2) ? tu : to_;
        bt[tid] = (bb[k] + tt[k]) * INV2PI;
    }
    __hip_atomic_store(&wcnt[tid], 0u, __ATOMIC_RELAXED, __HIP_MEMORY_SCOPE_AGENT);
}

// ---------------------------------------------------------------------------
// recurrence step (verbatim R2/R6-measured): DPP broadcast + cumprod-of-cos
// gate network. 1 batch per 16-lane group.
// ---------------------------------------------------------------------------
template<int CTRL>
__device__ __forceinline__ float fdpp(float x) {
    return __int_as_float(__builtin_amdgcn_update_dpp(
        0, __float_as_int(x), CTRL, 0xF, 0xF, true));
}

__device__ __forceinline__ float lstm_step(
    float& h, float& c, float zb,
    float wh0, float wh1, float wh2, float wh3,
    float s1c, float m2, float m3, int k, bool b0g, bool b1g)
{
    float h0 = fdpp<0x00>(h), h1 = fdpp<0x55>(h), h2 = fdpp<0xAA>(h), h3 = fdpp<0xFF>(h);
    float t1 = fmaf(h2, wh2, h3 * wh3);
    float z  = fmaf(h1, wh1, fmaf(h0, wh0, zb)) + t1;   // in revolutions

    float cs = __builtin_amdgcn_cosf(__builtin_amdgcn_fractf(z));

    float q0 = fdpp<0x00>(cs), q1 = fdpp<0x55>(cs), q2 = fdpp<0xAA>(cs);
    float p = (q0 * (k >= 1 ? q1 : 1.f)) * ((k >= 2 ? q2 : 1.f) * (k == 3 ? cs : 1.f));

    float e = __builtin_amdgcn_exp2f(p * s1c);
    float y = fmaf(__builtin_amdgcn_rcpf(1.f + e), m2, m3);

    float mm  = fdpp<0x1B>(y);
    float y4  = fdpp<0x141>(mm);
    float y8  = fdpp<0x128>(y);
    float y12 = fdpp<0x128>(y4);
    float t01  = b0g ? y4  : y,  t01s = b0g ? y  : y4;
    float t23  = b0g ? y12 : y8, t23s = b0g ? y8 : y12;
    float fv = b1g ? t23  : t01;
    float iv = b1g ? t23s : t01s;
    float gv = b1g ? t01  : t23;
    float ov = b1g ? t01s : t23s;

    c = fmaf(fv, c, iv * gv);
    float e2 = __builtin_amdgcn_exp2f(c * -2.885390082f);
    float th = fmaf(2.f, __builtin_amdgcn_rcpf(1.f + e2), -1.f);
    h = ov * th;
    return h;
}

// lane-0 acquire-RMW poll (RMW resolves at the coherence point -> never
// stale), broadcast to the wave, acquire fence before consuming Zx.
__device__ __forceinline__ void wave_poll(unsigned int* wcnt, int w, int lane) {
    for (;;) {
        unsigned v = 0;
        if (lane == 0)
            v = __hip_atomic_fetch_add(&wcnt[w], 0u, __ATOMIC_ACQUIRE,
                                       __HIP_MEMORY_SCOPE_AGENT);
        v = (unsigned)__builtin_amdgcn_readfirstlane((int)v);
        if (v >= (unsigned)TPW) break;
        __builtin_amdgcn_s_sleep(4);
    }
    __builtin_amdgcn_fence(__ATOMIC_ACQUIRE, "agent");
}

// ---------------------------------------------------------------------------
// Merged producer/consumer kernel (v8). R8 post-mortem: the handoff race was
// a COUNTING bug — the per-tile wcnt atomicAdd(+1) ran in all 64 lanes, so
// each tile bumped its window by 64 (m20: coalesced to +lane-count); windows
// hit the 128 threshold after 2/128 tiles and the consumer read unwritten Zx
// (absmax 1.24, bounded by sigmoid/tanh). Fix: lane 0 publishes with a
// RELEASE RMW; consumer polls via lane-0 ACQUIRE RMW. Structure unchanged:
// 256 blocks x 4 waves; wave 3 of blocks 192..255 = the 64 rec waves
// (verbatim R6 code, alone on their SIMD, setprio(2)); the other 960 waves
// run the PROVEN v5 gemm per 64-row tile, stride 960. Producers never wait
// -> deadlock-free; production outruns consumption ~4x.
// ---------------------------------------------------------------------------
__global__ __launch_bounds__(256) void qlstm_merged(
    const float4* __restrict__ x4,
    const float*  __restrict__ Wc,    // [128][16] packed, prescaled
    const float*  __restrict__ btv,   // [16] prescaled
    const float* __restrict__ Wf, const float* __restrict__ Wi,
    const float* __restrict__ Wu, const float* __restrict__ Wo,
    float* __restrict__ Zx,
    unsigned int* __restrict__ wcnt,
    float* __restrict__ out)
{
    __shared__ float xs[4][64 * 36];          // 4 x 9216 B (gemm waves only)
    const int bi   = blockIdx.x;
    const int wi   = threadIdx.x >> 6;
    const int lane = threadIdx.x & 63;
    const bool is_rec = (bi >= 192) && (wi == 3);

    if (!is_rec) {
        // ================= gemm role (v5, per-tile) =================
        float* myxs = xs[wi];
        const int rank = (bi < 192) ? (bi * 4 + wi) : (768 + (bi - 192) * 3 + wi);
        const int r0 = lane >> 3;             // 0..7
        const int q  = lane & 7;              // 0..7

        float acc0[16];
#pragma unroll
        for (int u = 0; u < 16; ++u) acc0[u] = btv[u];   // uniform -> s_load

        float4* Zx4 = (float4*)Zx;

        for (int tile = rank; tile < NTILES; tile += NGEMMW) {
            const size_t wrow0 = (size_t)tile * 64;
            float acc[16];
#pragma unroll
            for (int u = 0; u < 16; ++u) acc[u] = acc0[u];

#pragma unroll
            for (int c = 0; c < 4; ++c) {
                float4 v[8];
#pragma unroll
                for (int i = 0; i < 8; ++i)
                    v[i] = x4[(wrow0 + i * 8 + r0) * 32 + c * 8 + q];
#pragma unroll
                for (int i = 0; i < 8; ++i)
                    *(float4*)&myxs[(i * 8 + r0) * 36 + q * 4] = v[i];

                float xr[32];
#pragma unroll
                for (int j = 0; j < 8; ++j) {
                    float4 tv = *(const float4*)&myxs[lane * 36 + j * 4];
                    xr[j * 4 + 0] = tv.x; xr[j * 4 + 1] = tv.y;
                    xr[j * 4 + 2] = tv.z; xr[j * 4 + 3] = tv.w;
                }
#pragma unroll
                for (int dd = 0; dd < 32; ++dd) {
                    const float xv = xr[dd];
                    const float* w = &Wc[(c * 32 + dd) * 16];  // uniform -> s_load
#pragma unroll
                    for (int u = 0; u < 16; ++u) acc[u] = fmaf(xv, w[u], acc[u]);
                }
            }

            size_t orow = wrow0 + lane;
            float4* zr = &Zx4[orow * 4];
            zr[0] = make_float4(acc[0],  acc[1],  acc[2],  acc[3]);
            zr[1] = make_float4(acc[4],  acc[5],  acc[6],  acc[7]);
            zr[2] = make_float4(acc[8],  acc[9],  acc[10], acc[11]);
            zr[3] = make_float4(acc[12], acc[13], acc[14], acc[15]);

            // publish: drain+writeback stores, then ONE +1 per tile (lane 0),
            // release on the RMW itself.
            __builtin_amdgcn_fence(__ATOMIC_RELEASE, "agent");
            if (lane == 0)
                __hip_atomic_fetch_add(&wcnt[tile >> 7], 1u,
                                       __ATOMIC_RELEASE, __HIP_MEMORY_SCOPE_AGENT);
        }
    } else {
        // ================= rec role (verbatim R6 + polling) =================
        __builtin_amdgcn_s_setprio(2);        // insurance vs SIMD sharing

        const int u = lane & 15;
        const int g = u >> 2;
        const int k = u & 3;
        const int b = (bi - 192) * 4 + (lane >> 4);

        const float* Wg = (g == 0) ? Wf : (g == 1) ? Wi : (g == 2) ? Wu : Wo;
        const float wh0 = Wg[(DIM + 0) * 4 + k] * INV2PI;
        const float wh1 = Wg[(DIM + 1) * 4 + k] * INV2PI;
        const float wh2 = Wg[(DIM + 2) * 4 + k] * INV2PI;
        const float wh3 = Wg[(DIM + 3) * 4 + k] * INV2PI;

        const bool  isg = (g == 2);
        const float s1c = isg ? -2.885390082f : -1.442695041f;
        const float m2  = isg ? 2.f : 1.f;
        const float m3  = isg ? -1.f : 0.f;
        const bool  b0g = (g & 1) != 0;
        const bool  b1g = (g & 2) != 0;

        const float* zp = Zx + b * 16 + u;    // step stride B*16 = 4096
        const bool do_store = (u < 4);
        float* op = out + b * 4 + k;

        float h = 0.f, c = 0.f;

        wave_poll(wcnt, 0, lane);             // window 0 before first prefetch

        float zv[8];
#pragma unroll
        for (int i = 0; i < 8; ++i) zv[i] = zp[(size_t)i * 4096];

        int wcur = 0;
        for (int t = 0; t < T_STEPS; t += 8) {
            // loads this iter target steps t+8..t+15 -> need window (t+15)>>5
            int wneed = (t + 15) >> 5;
            if (wneed > wcur && wneed < NWIN) { wave_poll(wcnt, wneed, lane); wcur = wneed; }

#pragma unroll
            for (int j = 0; j < 8; ++j) {
                int tt = t + j;

                float o = lstm_step(h, c, zv[j], wh0, wh1, wh2, wh3, s1c, m2, m3, k, b0g, b1g);

                if (do_store) op[(size_t)tt * (BATCH * 4)] = o;

                int tn = tt + 8;
                if (tn > T_STEPS - 1) tn = T_STEPS - 1;
                zv[j] = zp[(size_t)tn * 4096];
            }
        }

        if (do_store) {
            size_t hx_off = (size_t)T_STEPS * BATCH * 4;
            out[hx_off + b * 4 + k] = h;
            out[hx_off + BATCH * 4 + b * 4 + k] = c;
        }
    }
}

extern "C" void kernel_launch(void* const* d_in, const int* in_sizes, int n_in,
                              void* d_out, int out_size, void* d_ws, size_t ws_size,
                              hipStream_t stream) {
    const float* x  = (const float*)d_in[0];
    const float* Wf = (const float*)d_in[1];
    const float* bf = (const float*)d_in[2];
    const float* tf = (const float*)d_in[3];
    const float* Wi = (const float*)d_in[4];
    const float* bi = (const float*)d_in[5];
    const float* ti = (const float*)d_in[6];
    const float* Wu = (const float*)d_in[7];
    const float* bu = (const float*)d_in[8];
    const float* tu = (const float*)d_in[9];
    const float* Wo = (const float*)d_in[10];
    const float* bo = (const float*)d_in[11];
    const float* to_ = (const float*)d_in[12];
    float* out = (float*)d_out;

    float* Zx = (float*)d_ws;                       // 33.5 MB
    float* Wc = Zx + ZX_FLOATS;                     // 8 KB
    float* bt = Wc + DIM * 16;                      // 64 B
    unsigned int* wcnt = (unsigned int*)(bt + 16);  // 64 counters

    prep<<<1, 64, 0, stream>>>(Wf, bf, tf, Wi, bi, ti, Wu, bu, tu, Wo, bo, to_,
                               Wc, bt, wcnt);

    qlstm_merged<<<256, 256, 0, stream>>>(
        (const float4*)x, Wc, bt, Wf, Wi, Wu, Wo, Zx, wcnt, out);
}

// Round 11
// 685.300 us; speedup vs baseline: 1.9121x; 1.9121x over previous
//
#include <hip/hip_runtime.h>
#include <hip/hip_bf16.h>

#define T_STEPS 2048
#define BATCH   256
#define DIM     128
#define INV2PI  0.15915494309189535f

#define ZX_FLOATS (T_STEPS * BATCH * 16)   // 33.5 MB

// ---------------------------------------------------------------------------
// prep: pack Wc[d*16+(g*4+k)] = W_g[d*4+k]/2pi, bt[u] = (b+theta)/2pi.
// ---------------------------------------------------------------------------
__global__ __launch_bounds__(64) void prep(
    const float* __restrict__ Wf, const float* __restrict__ bf, const float* __restrict__ tf,
    const float* __restrict__ Wi, const float* __restrict__ bi, const float* __restrict__ ti,
    const float* __restrict__ Wu, const float* __restrict__ bu, const float* __restrict__ tu,
    const float* __restrict__ Wo, const float* __restrict__ bo, const float* __restrict__ to_,
    float* __restrict__ Wc, float* __restrict__ bt)
{
    const int tid = threadIdx.x;
    for (int idx = tid; idx < DIM * 16; idx += 64) {
        int d = idx >> 4, u = idx & 15, g = u >> 2, k = u & 3;
        const float* W = (g == 0) ? Wf : (g == 1) ? Wi : (g == 2) ? Wu : Wo;
        Wc[idx] = W[d * 4 + k] * INV2PI;
    }
    if (tid < 16) {
        int g = tid >> 2, k = tid & 3;
        const float* bb = (g == 0) ? bf : (g == 1) ? bi : (g == 2) ? bu : bo;
        const float* tt = (g == 0) ? tf : (g == 1) ? ti : (g == 2) ? tu : to_;
        bt[tid] = (bb[k] + tt[k]) * INV2PI;
    }
}

// ---------------------------------------------------------------------------
// Kernel 1 v7 (direct-load): R9 showed v5's 102us depends on 16 waves/CU to
// hide SMEM stalls; its LDS exists ONLY to transpose coalesced loads into
// lane-owns-row. Direct version: lane reads its OWN row, 8x dwordx4 per
// 32-d chunk = 128B contiguous per lane. Per-instr addresses are 512B-strided
// but every 64B line is fully consumed across the unroll (64-way streaming,
// zero over-fetch). No LDS, ~60 VGPR -> launch_bounds(256,6) = 24 waves/CU
// (1.5x v5's TLP). FMA order over (dd,u) identical to v5 -> bit-identical z.
// Floors: HBM 43us (268MB x), issue ~14us. Predict 55-75us (v5: 102).
// ---------------------------------------------------------------------------
__global__ __launch_bounds__(256, 6) void zx_gemm(
    const float4* __restrict__ x4,
    const float*  __restrict__ Wc,    // [128][16] packed, prescaled
    const float*  __restrict__ btv,   // [16] prescaled
    float4*       __restrict__ Zx4)
{
    const size_t row = (size_t)blockIdx.x * 256 + threadIdx.x;

    float acc[16];
#pragma unroll
    for (int u = 0; u < 16; ++u) acc[u] = btv[u];   // uniform -> s_load

    const float4* xp = &x4[row * 32];

#pragma unroll
    for (int c = 0; c < 4; ++c) {
        float4 xv[8];
#pragma unroll
        for (int j = 0; j < 8; ++j) xv[j] = xp[c * 8 + j];
#pragma unroll
        for (int j = 0; j < 8; ++j) {
            const float* w = &Wc[(c * 32 + j * 4) * 16];   // uniform -> s_load
#pragma unroll
            for (int u = 0; u < 16; ++u) acc[u] = fmaf(xv[j].x, w[u],      acc[u]);
#pragma unroll
            for (int u = 0; u < 16; ++u) acc[u] = fmaf(xv[j].y, w[16 + u], acc[u]);
#pragma unroll
            for (int u = 0; u < 16; ++u) acc[u] = fmaf(xv[j].z, w[32 + u], acc[u]);
#pragma unroll
            for (int u = 0; u < 16; ++u) acc[u] = fmaf(xv[j].w, w[48 + u], acc[u]);
        }
    }

    float4* zr = &Zx4[row * 4];
    zr[0] = make_float4(acc[0],  acc[1],  acc[2],  acc[3]);
    zr[1] = make_float4(acc[4],  acc[5],  acc[6],  acc[7]);
    zr[2] = make_float4(acc[8],  acc[9],  acc[10], acc[11]);
    zr[3] = make_float4(acc[12], acc[13], acc[14], acc[15]);
}

// ---------------------------------------------------------------------------
// Kernel 2 (verbatim R2/R6-measured 292-298us): 1 chain per 16-lane group,
// 64 blocks x 64 thr, depth-8 z prefetch. Latency-bound at ~350 cyc/step.
// ---------------------------------------------------------------------------
template<int CTRL>
__device__ __forceinline__ float fdpp(float x) {
    return __int_as_float(__builtin_amdgcn_update_dpp(
        0, __float_as_int(x), CTRL, 0xF, 0xF, true));
}

__device__ __forceinline__ float lstm_step(
    float& h, float& c, float zb,
    float wh0, float wh1, float wh2, float wh3,
    float s1c, float m2, float m3, int k, bool b0g, bool b1g)
{
    float h0 = fdpp<0x00>(h), h1 = fdpp<0x55>(h), h2 = fdpp<0xAA>(h), h3 = fdpp<0xFF>(h);
    float t1 = fmaf(h2, wh2, h3 * wh3);
    float z  = fmaf(h1, wh1, fmaf(h0, wh0, zb)) + t1;   // in revolutions

    float cs = __builtin_amdgcn_cosf(__builtin_amdgcn_fractf(z));

    float q0 = fdpp<0x00>(cs), q1 = fdpp<0x55>(cs), q2 = fdpp<0xAA>(cs);
    float p = (q0 * (k >= 1 ? q1 : 1.f)) * ((k >= 2 ? q2 : 1.f) * (k == 3 ? cs : 1.f));

    float e = __builtin_amdgcn_exp2f(p * s1c);
    float y = fmaf(__builtin_amdgcn_rcpf(1.f + e), m2, m3);

    float mm  = fdpp<0x1B>(y);
    float y4  = fdpp<0x141>(mm);
    float y8  = fdpp<0x128>(y);
    float y12 = fdpp<0x128>(y4);
    float t01  = b0g ? y4  : y,  t01s = b0g ? y  : y4;
    float t23  = b0g ? y12 : y8, t23s = b0g ? y8 : y12;
    float fv = b1g ? t23  : t01;
    float iv = b1g ? t23s : t01s;
    float gv = b1g ? t01  : t23;
    float ov = b1g ? t01s : t23s;

    c = fmaf(fv, c, iv * gv);
    float e2 = __builtin_amdgcn_exp2f(c * -2.885390082f);
    float th = fmaf(2.f, __builtin_amdgcn_rcpf(1.f + e2), -1.f);
    h = ov * th;
    return h;
}

__global__ __launch_bounds__(64) void qlstm_rec(
    const float* __restrict__ Zx,
    const float* __restrict__ Wf, const float* __restrict__ Wi,
    const float* __restrict__ Wu, const float* __restrict__ Wo,
    float* __restrict__ out)
{
    const int tid = threadIdx.x;
    const int u   = tid & 15;
    const int g   = u >> 2;
    const int k   = u & 3;
    const int b   = blockIdx.x * 4 + (tid >> 4);   // 64 blocks x 4 batches

    const float* Wg = (g == 0) ? Wf : (g == 1) ? Wi : (g == 2) ? Wu : Wo;
    const float wh0 = Wg[(DIM + 0) * 4 + k] * INV2PI;
    const float wh1 = Wg[(DIM + 1) * 4 + k] * INV2PI;
    const float wh2 = Wg[(DIM + 2) * 4 + k] * INV2PI;
    const float wh3 = Wg[(DIM + 3) * 4 + k] * INV2PI;

    const bool  isg = (g == 2);
    const float s1c = isg ? -2.885390082f : -1.442695041f;
    const float m2  = isg ? 2.f : 1.f;
    const float m3  = isg ? -1.f : 0.f;
    const bool  b0g = (g & 1) != 0;
    const bool  b1g = (g & 2) != 0;

    const float* zp = Zx + b * 16 + u;      // step stride B*16 = 4096
    const bool do_store = (u < 4);
    float* op = out + b * 4 + k;

    float h = 0.f, c = 0.f;

    float zv[8];
#pragma unroll
    for (int i = 0; i < 8; ++i) zv[i] = zp[(size_t)i * 4096];

    for (int t = 0; t < T_STEPS; t += 8) {
#pragma unroll
        for (int j = 0; j < 8; ++j) {
            int tt = t + j;

            float o = lstm_step(h, c, zv[j], wh0, wh1, wh2, wh3, s1c, m2, m3, k, b0g, b1g);

            if (do_store) op[(size_t)tt * (BATCH * 4)] = o;

            int tn = tt + 8;
            if (tn > T_STEPS - 1) tn = T_STEPS - 1;
            zv[j] = zp[(size_t)tn * 4096];
        }
    }

    if (do_store) {
        size_t hx_off = (size_t)T_STEPS * BATCH * 4;
        out[hx_off + b * 4 + k] = h;
        out[hx_off + BATCH * 4 + b * 4 + k] = c;
    }
}

extern "C" void kernel_launch(void* const* d_in, const int* in_sizes, int n_in,
                              void* d_out, int out_size, void* d_ws, size_t ws_size,
                              hipStream_t stream) {
    const float* x  = (const float*)d_in[0];
    const float* Wf = (const float*)d_in[1];
    const float* bf = (const float*)d_in[2];
    const float* tf = (const float*)d_in[3];
    const float* Wi = (const float*)d_in[4];
    const float* bi = (const float*)d_in[5];
    const float* ti = (const float*)d_in[6];
    const float* Wu = (const float*)d_in[7];
    const float* bu = (const float*)d_in[8];
    const float* tu = (const float*)d_in[9];
    const float* Wo = (const float*)d_in[10];
    const float* bo = (const float*)d_in[11];
    const float* to_ = (const float*)d_in[12];
    float* out = (float*)d_out;

    float* Zx = (float*)d_ws;                       // 33.5 MB
    float* Wc = Zx + ZX_FLOATS;                     // 8 KB
    float* bt = Wc + DIM * 16;                      // 64 B

    prep<<<1, 64, 0, stream>>>(Wf, bf, tf, Wi, bi, ti, Wu, bu, tu, Wo, bo, to_, Wc, bt);

    zx_gemm<<<(T_STEPS * BATCH) / 256, 256, 0, stream>>>(
        (const float4*)x, Wc, bt, (float4*)Zx);

    qlstm_rec<<<BATCH / 4, 64, 0, stream>>>(Zx, Wf, Wi, Wu, Wo, out);
}

// Round 12
// 640.782 us; speedup vs baseline: 2.0449x; 1.0695x over previous
//
#include <hip/hip_runtime.h>
#include <hip/hip_bf16.h>

#define T_STEPS 2048
#define BATCH   256
#define DIM     128
#define INV2PI  0.15915494309189535f

#define ZX_FLOATS (T_STEPS * BATCH * 16)   // 33.5 MB

// ---------------------------------------------------------------------------
// prep: NEW lane layout u = k*4+g (unit-major). Wc[d*16 + (k*4+g)] =
// W_g[d*4+k]/2pi, bt[k*4+g] = (b_g[k]+theta_g[k])/2pi. The gemm consumes
// Wc/bt generically by u, so Zx comes out in the new layout for free.
// ---------------------------------------------------------------------------
__global__ __launch_bounds__(64) void prep(
    const float* __restrict__ Wf, const float* __restrict__ bf, const float* __restrict__ tf,
    const float* __restrict__ Wi, const float* __restrict__ bi, const float* __restrict__ ti,
    const float* __restrict__ Wu, const float* __restrict__ bu, const float* __restrict__ tu,
    const float* __restrict__ Wo, const float* __restrict__ bo, const float* __restrict__ to_,
    float* __restrict__ Wc, float* __restrict__ bt)
{
    const int tid = threadIdx.x;
    for (int idx = tid; idx < DIM * 16; idx += 64) {
        int d = idx >> 4, u = idx & 15, g = u & 3, k = u >> 2;
        const float* W = (g == 0) ? Wf : (g == 1) ? Wi : (g == 2) ? Wu : Wo;
        Wc[idx] = W[d * 4 + k] * INV2PI;
    }
    if (tid < 16) {
        int g = tid & 3, k = tid >> 2;
        const float* bb = (g == 0) ? bf : (g == 1) ? bi : (g == 2) ? bu : bo;
        const float* tt = (g == 0) ? tf : (g == 1) ? ti : (g == 2) ? tu : to_;
        bt[tid] = (bb[k] + tt[k]) * INV2PI;
    }
}

// ---------------------------------------------------------------------------
// Kernel 1: verbatim v5 gemm (R2-measured ~102us inside 677 total). R11
// proved the direct-load variant is 15us WORSE (DRAM burst efficiency);
// gemm is at its practical floor -- do not touch.
// ---------------------------------------------------------------------------
__global__ __launch_bounds__(256) void zx_gemm(
    const float4* __restrict__ x4,
    const float*  __restrict__ Wc,    // [128][16] packed, prescaled
    const float*  __restrict__ btv,   // [16] prescaled
    float4*       __restrict__ Zx4)
{
    __shared__ float xs[4][64 * 36];          // 36864 B total
    const int lane = threadIdx.x & 63;
    const int wid  = threadIdx.x >> 6;
    float* myxs = xs[wid];
    const size_t wrow0 = ((size_t)blockIdx.x * 4 + wid) * 64;

    float acc[16];
#pragma unroll
    for (int u = 0; u < 16; ++u) acc[u] = btv[u];   // uniform -> s_load

    const int r0 = lane >> 3;                 // 0..7
    const int q  = lane & 7;                  // 0..7

#pragma unroll
    for (int c = 0; c < 4; ++c) {
        float4 v[8];
#pragma unroll
        for (int i = 0; i < 8; ++i)
            v[i] = x4[(wrow0 + i * 8 + r0) * 32 + c * 8 + q];
#pragma unroll
        for (int i = 0; i < 8; ++i)
            *(float4*)&myxs[(i * 8 + r0) * 36 + q * 4] = v[i];

        float xr[32];
#pragma unroll
        for (int j = 0; j < 8; ++j) {
            float4 tv = *(const float4*)&myxs[lane * 36 + j * 4];
            xr[j * 4 + 0] = tv.x; xr[j * 4 + 1] = tv.y;
            xr[j * 4 + 2] = tv.z; xr[j * 4 + 3] = tv.w;
        }
#pragma unroll
        for (int dd = 0; dd < 32; ++dd) {
            const float xv = xr[dd];
            const float* w = &Wc[(c * 32 + dd) * 16]; // uniform -> s_load
#pragma unroll
            for (int u = 0; u < 16; ++u) acc[u] = fmaf(xv, w[u], acc[u]);
        }
    }

    size_t orow = wrow0 + lane;
    float4* zr = &Zx4[orow * 4];
    zr[0] = make_float4(acc[0],  acc[1],  acc[2],  acc[3]);
    zr[1] = make_float4(acc[4],  acc[5],  acc[6],  acc[7]);
    zr[2] = make_float4(acc[8],  acc[9],  acc[10], acc[11]);
    zr[3] = make_float4(acc[12], acc[13], acc[14], acc[15]);
}

// ---------------------------------------------------------------------------
// Kernel 2 v5 (unit-major layout): lane u = k*4+g. The 4 gates of unit k
// now form a QUAD -> the old mm/y4/y12 redistribution network (2-deep DPP
// + 8 cndmask + b0g/b1g) collapses to 4 parallel quad-broadcasts.
//  - cumprod: row_shr:4j with PERSISTENT old=1.0 register (masked lanes
//    keep 1.0 forever, seeded once) -- scan-idiom semantics dst[i]=src[i-N].
//  - h-dot: row_ror:4j (wrapped, all-valid) paired with wh[(k-j)&3].
// ~35 VALU/step vs ~50 -> predict 341 -> ~240 cyc/step.
// ---------------------------------------------------------------------------
template<int CTRL, bool BC>
__device__ __forceinline__ float fdpp2(float old, float x) {
    return __int_as_float(__builtin_amdgcn_update_dpp(
        __float_as_int(old), __float_as_int(x), CTRL, 0xF, 0xF, BC));
}
template<int CTRL>
__device__ __forceinline__ float fdpp(float x) {
    return __int_as_float(__builtin_amdgcn_update_dpp(
        0, __float_as_int(x), CTRL, 0xF, 0xF, true));
}

__device__ __forceinline__ float lstm_step(
    float& h, float& c, float& cm1, float& cm2, float& cm3, float zb,
    float whr0, float whr1, float whr2, float whr3,
    float s1c, float m2, float m3)
{
    float za  = fmaf(h, whr0, zb);
    float hr1 = fdpp<0x124>(h);               // row_ror:4  -> h[(k-1)&3]
    float hr2 = fdpp<0x128>(h);               // row_ror:8  -> h[(k-2)&3]
    float hr3 = fdpp<0x12C>(h);               // row_ror:12 -> h[(k-3)&3]
    float t1  = fmaf(hr2, whr2, hr3 * whr3);
    float z   = fmaf(hr1, whr1, za) + t1;     // in revolutions

    float cs = __builtin_amdgcn_cosf(__builtin_amdgcn_fractf(z));

    // persistent-old masked shifts: invalid lanes (k<j) keep their seeded 1.0
    cm1 = fdpp2<0x114, false>(cm1, cs);       // row_shr:4  -> cos[k-1]
    cm2 = fdpp2<0x118, false>(cm2, cs);       // row_shr:8  -> cos[k-2]
    cm3 = fdpp2<0x11C, false>(cm3, cs);       // row_shr:12 -> cos[k-3]
    float p = (cs * cm1) * (cm2 * cm3);

    float e = __builtin_amdgcn_exp2f(p * s1c);
    float y = fmaf(__builtin_amdgcn_rcpf(1.f + e), m2, m3);

    float fv = fdpp<0x00>(y);                 // quad lane 0 = forget
    float iv = fdpp<0x55>(y);                 // quad lane 1 = input
    float gv = fdpp<0xAA>(y);                 // quad lane 2 = update
    float ov = fdpp<0xFF>(y);                 // quad lane 3 = output

    c = fmaf(fv, c, iv * gv);
    float e2 = __builtin_amdgcn_exp2f(c * -2.885390082f);
    float th = fmaf(2.f, __builtin_amdgcn_rcpf(1.f + e2), -1.f);
    h = ov * th;
    return h;
}

__global__ __launch_bounds__(64) void qlstm_rec(
    const float* __restrict__ Zx,
    const float* __restrict__ Wf, const float* __restrict__ Wi,
    const float* __restrict__ Wu, const float* __restrict__ Wo,
    float* __restrict__ out)
{
    const int tid = threadIdx.x;
    const int u   = tid & 15;
    const int g   = u & 3;                    // NEW: unit-major layout
    const int k   = u >> 2;
    const int b   = blockIdx.x * 4 + (tid >> 4);   // 64 blocks x 4 batches

    const float* Wg = (g == 0) ? Wf : (g == 1) ? Wi : (g == 2) ? Wu : Wo;
    // whr[j] pairs with h[(k-j)&3] (row_ror:4j under dst[i]=src[i-N])
    const float whr0 = Wg[(DIM + k)            * 4 + k] * INV2PI;
    const float whr1 = Wg[(DIM + ((k + 3) & 3)) * 4 + k] * INV2PI;
    const float whr2 = Wg[(DIM + ((k + 2) & 3)) * 4 + k] * INV2PI;
    const float whr3 = Wg[(DIM + ((k + 1) & 3)) * 4 + k] * INV2PI;

    const bool  isg = (g == 2);
    const float s1c = isg ? -2.885390082f : -1.442695041f;
    const float m2  = isg ? 2.f : 1.f;
    const float m3  = isg ? -1.f : 0.f;

    const float* zp = Zx + b * 16 + u;      // step stride B*16 = 4096
    const bool do_store = (g == 0);         // lanes 0,4,8,12: write unit k
    float* op = out + b * 4 + k;

    float h = 0.f, c = 0.f;
    float cm1 = 1.f, cm2 = 1.f, cm3 = 1.f;  // persistent masked-DPP registers

    float zv[8];
#pragma unroll
    for (int i = 0; i < 8; ++i) zv[i] = zp[(size_t)i * 4096];

    for (int t = 0; t < T_STEPS; t += 8) {
#pragma unroll
        for (int j = 0; j < 8; ++j) {
            int tt = t + j;

            float o = lstm_step(h, c, cm1, cm2, cm3, zv[j],
                                whr0, whr1, whr2, whr3, s1c, m2, m3);

            if (do_store) op[(size_t)tt * (BATCH * 4)] = o;

            int tn = tt + 8;
            if (tn > T_STEPS - 1) tn = T_STEPS - 1;
            zv[j] = zp[(size_t)tn * 4096];
        }
    }

    if (do_store) {
        size_t hx_off = (size_t)T_STEPS * BATCH * 4;
        out[hx_off + b * 4 + k] = h;
        out[hx_off + BATCH * 4 + b * 4 + k] = c;
    }
}

extern "C" void kernel_launch(void* const* d_in, const int* in_sizes, int n_in,
                              void* d_out, int out_size, void* d_ws, size_t ws_size,
                              hipStream_t stream) {
    const float* x  = (const float*)d_in[0];
    const float* Wf = (const float*)d_in[1];
    const float* bf = (const float*)d_in[2];
    const float* tf = (const float*)d_in[3];
    const float* Wi = (const float*)d_in[4];
    const float* bi = (const float*)d_in[5];
    const float* ti = (const float*)d_in[6];
    const float* Wu = (const float*)d_in[7];
    const float* bu = (const float*)d_in[8];
    const float* tu = (const float*)d_in[9];
    const float* Wo = (const float*)d_in[10];
    const float* bo = (const float*)d_in[11];
    const float* to_ = (const float*)d_in[12];
    float* out = (float*)d_out;

    float* Zx = (float*)d_ws;                       // 33.5 MB
    float* Wc = Zx + ZX_FLOATS;                     // 8 KB
    float* bt = Wc + DIM * 16;                      // 64 B

    prep<<<1, 64, 0, stream>>>(Wf, bf, tf, Wi, bi, ti, Wu, bu, tu, Wo, bo, to_, Wc, bt);

    zx_gemm<<<(T_STEPS * BATCH) / 256, 256, 0, stream>>>(
        (const float4*)x, Wc, bt, (float4*)Zx);

    qlstm_rec<<<BATCH / 4, 64, 0, stream>>>(Zx, Wf, Wi, Wu, Wo, out);
}